// Round 7
// baseline (292.961 us; speedup 1.0000x reference)
//
#include <hip/hip_runtime.h>

#define IN_FEATS 128
#define OUT_FEATS 64
#define TM 64              // rows per linear block
#define FS_LD 132          // padded LDS leading dim
#define BW_LOG 6           // bucket width = 64 nodes
#define BWIDTH 64
#define MAX_NB 1024
#define SE_PER_BLK 4096    // edges staged per block (256 thr x 16)
#define MAX_BUCKET 4096    // records per bucket in bin_sort LDS (32 KB)
#define PAD_ALLOC 1376     // per-bucket region slack (196 blocks x 7, 8-aligned)

__device__ inline void fma4(float4& a, float s, const float4& v) {
    a.x += s * v.x; a.y += s * v.y; a.z += s * v.z; a.w += s * v.w;
}
__device__ inline unsigned short f2bf(float f) {   // RTNE fp32 -> bf16
    unsigned u = __float_as_uint(f);
    u += 0x7FFFu + ((u >> 16) & 1u);
    return (unsigned short)(u >> 16);
}
__device__ inline float bf2f(unsigned short v) {
    return __uint_as_float(((unsigned)v) << 16);
}

// ------- Linear (h = bf16(feat@W^T+b)) fused with coarse dst-histogram -------
__global__ __launch_bounds__(256) void linear_hist(
    const float* __restrict__ feat, const float* __restrict__ W,
    const float* __restrict__ b, unsigned short* __restrict__ h,
    const int* __restrict__ edst, int* __restrict__ ghist,
    int n_nodes, int n_edges, int nb)
{
    __shared__ float fs[TM * FS_LD];
    __shared__ float wt[IN_FEATS * OUT_FEATS];
    __shared__ int hist[MAX_NB];
    const int tid  = threadIdx.x;
    const int row0 = blockIdx.x * TM;

    for (int i = tid; i < nb; i += 256) hist[i] = 0;
    __syncthreads();

    {   // stage Wt
        const int c  = tid & 63;
        const int kb = (tid >> 6) * 32;
        const float4* wrow = (const float4*)(W + (size_t)c * IN_FEATS + kb);
#pragma unroll
        for (int i = 0; i < 8; ++i) {
            float4 t = wrow[i];
            int k = kb + i * 4;
            wt[(k + 0) * OUT_FEATS + c] = t.x;
            wt[(k + 1) * OUT_FEATS + c] = t.y;
            wt[(k + 2) * OUT_FEATS + c] = t.z;
            wt[(k + 3) * OUT_FEATS + c] = t.w;
        }
    }
    {   // stage feat tile
#pragma unroll
        for (int i = 0; i < 8; ++i) {
            int flat = i * 256 + tid;
            int r  = flat >> 5;
            int kc = flat & 31;
            int gr = row0 + r;
            float4 t = (gr < n_nodes)
                ? ((const float4*)(feat + (size_t)gr * IN_FEATS))[kc]
                : make_float4(0.f, 0.f, 0.f, 0.f);
            *((float4*)&fs[r * FS_LD + kc * 4]) = t;
        }
    }
    {   // fused histogram (independent of GEMM; overlaps FMA work)
        const int n4 = n_edges >> 2;
        const int4* ed4 = (const int4*)edst;
        for (int i = blockIdx.x * 256 + tid; i < n4; i += gridDim.x * 256) {
            int4 d = ed4[i];
            atomicAdd(&hist[d.x >> BW_LOG], 1);
            atomicAdd(&hist[d.y >> BW_LOG], 1);
            atomicAdd(&hist[d.z >> BW_LOG], 1);
            atomicAdd(&hist[d.w >> BW_LOG], 1);
        }
        if (blockIdx.x == 0 && tid < (n_edges & 3))
            atomicAdd(&hist[edst[n4 * 4 + tid] >> BW_LOG], 1);
    }
    __syncthreads();
    for (int i = tid; i < nb; i += 256)
        if (hist[i]) atomicAdd(&ghist[i], hist[i]);

    const int tx = tid & 15;
    const int ty = tid >> 4;

    float4 acc[4];
#pragma unroll
    for (int i = 0; i < 4; ++i) acc[i] = make_float4(0.f, 0.f, 0.f, 0.f);

    for (int k = 0; k < IN_FEATS; k += 4) {
        float4 fv[4], wv[4];
#pragma unroll
        for (int i = 0; i < 4; ++i)
            fv[i] = *((const float4*)&fs[(ty * 4 + i) * FS_LD + k]);
#pragma unroll
        for (int j = 0; j < 4; ++j)
            wv[j] = *((const float4*)&wt[(k + j) * OUT_FEATS + tx * 4]);
#pragma unroll
        for (int i = 0; i < 4; ++i) {
            fma4(acc[i], fv[i].x, wv[0]);
            fma4(acc[i], fv[i].y, wv[1]);
            fma4(acc[i], fv[i].z, wv[2]);
            fma4(acc[i], fv[i].w, wv[3]);
        }
    }

    float4 b4 = ((const float4*)b)[tx];
#pragma unroll
    for (int i = 0; i < 4; ++i) {
        int r = row0 + ty * 4 + i;
        if (r < n_nodes) {
            float4 o = acc[i];
            o.x += b4.x; o.y += b4.y; o.z += b4.z; o.w += b4.w;
            ushort4 s4;
            s4.x = f2bf(o.x); s4.y = f2bf(o.y);
            s4.z = f2bf(o.z); s4.w = f2bf(o.w);
            *((ushort4*)&h[(size_t)r * OUT_FEATS + tx * 4]) = s4;
        }
    }
}

// ------- Scan: bucket region spacing = hist + PAD_ALLOC slack -------
__global__ __launch_bounds__(256) void coarse_scan(
    const int* __restrict__ ghist, int* __restrict__ goff,
    int* __restrict__ gcur, int nb)
{
    __shared__ int wsum[4];
    __shared__ int wpre[4];
    const int tid  = threadIdx.x;
    const int lane = tid & 63;
    const int wv   = tid >> 6;
    int i0 = tid * 4;
    int v[4];
    int s = 0;
#pragma unroll
    for (int j = 0; j < 4; ++j)
        v[j] = (i0 + j < nb) ? (ghist[i0 + j] + PAD_ALLOC) : 0;
#pragma unroll
    for (int j = 0; j < 4; ++j) { int t = v[j]; v[j] = s; s += t; }
    int inc = s;
    for (int off = 1; off < 64; off <<= 1) {
        int t = __shfl_up(inc, off, 64);
        if (lane >= off) inc += t;
    }
    int wexcl = inc - s;
    if (lane == 63) wsum[wv] = inc;
    __syncthreads();
    if (tid == 0) {
        int a = 0;
        for (int k = 0; k < 4; ++k) { wpre[k] = a; a += wsum[k]; }
    }
    __syncthreads();
    int tbase = wpre[wv] + wexcl;
#pragma unroll
    for (int j = 0; j < 4; ++j) {
        int idx = i0 + j;
        if (idx < nb) { int e = tbase + v[j]; goff[idx] = e; gcur[idx] = e; }
    }
    if (tid == 0) goff[nb] = wpre[3] + wsum[3];
}

// ------- Stage: bin edges by bucket; allocations rounded to 8 (64 B lines),
//         slack filled with w=0 pad records (harmless in the sum). -------
__global__ __launch_bounds__(256) void stage_kernel(
    const int* __restrict__ esrc, const int* __restrict__ edst,
    const float* __restrict__ ew, int* __restrict__ gcur,
    int2* __restrict__ gstage, int n_edges, int nb)
{
    __shared__ int cnt[MAX_NB];
    __shared__ int base[MAX_NB];
    const int tid = threadIdx.x;
    const int e0  = blockIdx.x * SE_PER_BLK;

    for (int i = tid; i < nb; i += 256) cnt[i] = 0;
    __syncthreads();

    int key[16]; float w[16]; int bk[16]; int rk[16];
#pragma unroll
    for (int i = 0; i < 16; ++i) {
        int e = e0 + i * 256 + tid;
        if (e < n_edges) {
            int d = edst[e];
            int b = d >> BW_LOG;
            bk[i]  = b;
            key[i] = ((d & (BWIDTH - 1)) << 16) | esrc[e];
            w[i]   = ew[e];
            rk[i]  = atomicAdd(&cnt[b], 1);
        } else bk[i] = -1;
    }
    __syncthreads();
    for (int i = tid; i < nb; i += 256) {
        int c = cnt[i];
        if (c) {
            int alloc = (c + 7) & ~7;
            int bs = atomicAdd(&gcur[i], alloc);
            base[i] = bs;
            // pad slack with zero-weight records spread across the 64 nodes
            for (int j = c; j < alloc; ++j)
                gstage[bs + j] = make_int2((j & 63) << 16, 0);
        }
    }
    __syncthreads();
#pragma unroll
    for (int i = 0; i < 16; ++i) {
        if (bk[i] >= 0)
            gstage[base[bk[i]] + rk[i]] = make_int2(key[i], __float_as_int(w[i]));
    }
}

// ------- Bin-sort: bucket -> per-node segments (in place); explicit
//         (start,end) per node since regions have slack. -------
__global__ __launch_bounds__(256) void bin_sort(
    int2* __restrict__ gstage, const int* __restrict__ goff,
    const int* __restrict__ gcur, int2* __restrict__ seg, int n_nodes, int nb)
{
    __shared__ int2 recs[MAX_BUCKET];
    __shared__ int cnt[BWIDTH];
    __shared__ int cur[BWIDTH];
    const int tid = threadIdx.x;
    const int b   = blockIdx.x;
    const int s0  = goff[b];
    const int m   = gcur[b] - s0;   // real + pad records

    if (tid < BWIDTH) cnt[tid] = 0;
    __syncthreads();

    for (int i = tid; i < m; i += 256) {
        int2 r = gstage[s0 + i];
        recs[i] = r;
        atomicAdd(&cnt[(r.x >> 16) & 63], 1);
    }
    __syncthreads();

    if (tid < 64) {
        int v = cnt[tid];
        int inc = v;
        for (int o = 1; o < 64; o <<= 1) {
            int t = __shfl_up(inc, o, 64);
            if (tid >= o) inc += t;
        }
        int excl = inc - v;
        cur[tid] = excl;
        int node = b * BWIDTH + tid;
        if (node < n_nodes) seg[node] = make_int2(s0 + excl, s0 + excl + v);
    }
    __syncthreads();

    for (int i = tid; i < m; i += 256) {
        int2 r = recs[i];
        int pos = atomicAdd(&cur[(r.x >> 16) & 63], 1);
        gstage[s0 + pos] = r;
    }
}

// ------- Gather: one wave per dst node over its segment -------
__global__ __launch_bounds__(256) void gather_kernel(
    const unsigned short* __restrict__ h, const int2* __restrict__ seg,
    const int2* __restrict__ perm2, float* __restrict__ out, int n_nodes)
{
    int wave = (blockIdx.x * blockDim.x + threadIdx.x) >> 6;
    int lane = threadIdx.x & 63;
    if (wave >= n_nodes) return;
    int2 se = seg[wave];
    float acc = 0.f;
    int idx = se.x;
    for (; idx + 7 < se.y; idx += 8) {
        int2 r[8]; float hv[8];
#pragma unroll
        for (int u = 0; u < 8; ++u) r[u] = perm2[idx + u];
#pragma unroll
        for (int u = 0; u < 8; ++u)
            hv[u] = bf2f(h[(size_t)(r[u].x & 0xFFFF) * OUT_FEATS + lane]);
#pragma unroll
        for (int u = 0; u < 8; ++u)
            acc += hv[u] * __int_as_float(r[u].y);
    }
    for (; idx < se.y; ++idx) {
        int2 m = perm2[idx];
        acc += bf2f(h[(size_t)(m.x & 0xFFFF) * OUT_FEATS + lane])
               * __int_as_float(m.y);
    }
    out[(size_t)wave * OUT_FEATS + lane] = acc;
}

// ------- Fallback atomic scatter (needs separate linear w/o hist) -------
__global__ __launch_bounds__(256) void scatter_kernel(
    const unsigned short* __restrict__ h, const int* __restrict__ esrc,
    const int* __restrict__ edst, const float* __restrict__ ew,
    float* __restrict__ out, int n_edges)
{
    const int lane = threadIdx.x & 63;
    const int wave = threadIdx.x >> 6;
    const int stride = gridDim.x * 4;
    for (int e = blockIdx.x * 4 + wave; e < n_edges; e += stride) {
        const int s = esrc[e];
        const int d = edst[e];
        const float w = ew[e];
        atomicAdd(out + (size_t)d * OUT_FEATS + lane,
                  bf2f(h[(size_t)s * OUT_FEATS + lane]) * w);
    }
}

extern "C" void kernel_launch(void* const* d_in, const int* in_sizes, int n_in,
                              void* d_out, int out_size, void* d_ws, size_t ws_size,
                              hipStream_t stream) {
    const float* feat = (const float*)d_in[0];
    const int*   esrc = (const int*)d_in[1];
    const int*   edst = (const int*)d_in[2];
    const float* ew   = (const float*)d_in[3];
    const float* W    = (const float*)d_in[4];
    const float* b    = (const float*)d_in[5];
    float* out = (float*)d_out;

    const int n_nodes = in_sizes[0] / IN_FEATS;  // 50000
    const int n_edges = in_sizes[1];             // 800000
    const int nb = (n_nodes + BWIDTH - 1) >> BW_LOG;  // 782
    const int nlin = (n_nodes + TM - 1) / TM;         // 782 linear blocks

    // ws: h(bf16) | ghist(nb) | goff(nb+1) | gcur(nb) | seg(n int2) | gstage
    char* wsb = (char*)d_ws;
    unsigned short* h = (unsigned short*)wsb;
    size_t off_ghist = (((size_t)n_nodes * OUT_FEATS * sizeof(unsigned short)) + 15) & ~(size_t)15;
    size_t sz_ghist  = (((size_t)nb * sizeof(int)) + 15) & ~(size_t)15;
    size_t off_goff  = off_ghist + sz_ghist;
    size_t sz_goff   = (((size_t)(nb + 1) * sizeof(int)) + 15) & ~(size_t)15;
    size_t off_gcur  = off_goff + sz_goff;
    size_t sz_gcur   = (((size_t)nb * sizeof(int)) + 15) & ~(size_t)15;
    size_t off_seg   = off_gcur + sz_gcur;
    size_t sz_seg    = (((size_t)n_nodes * sizeof(int2)) + 15) & ~(size_t)15;
    size_t off_stage = off_seg + sz_seg;
    size_t n_slots   = (size_t)n_edges + (size_t)nb * PAD_ALLOC;
    size_t needed    = off_stage + n_slots * sizeof(int2);

    bool binnable = (nb <= MAX_NB) && (n_nodes < 65536) &&
                    ((size_t)n_edges / (size_t)nb * 2 + PAD_ALLOC + 256 <= MAX_BUCKET);

    if (ws_size >= needed && binnable) {
        int*  ghist  = (int*)(wsb + off_ghist);
        int*  goff   = (int*)(wsb + off_goff);
        int*  gcur   = (int*)(wsb + off_gcur);
        int2* seg    = (int2*)(wsb + off_seg);
        int2* gstage = (int2*)(wsb + off_stage);
        hipMemsetAsync(ghist, 0, (size_t)nb * sizeof(int), stream);
        linear_hist<<<nlin, 256, 0, stream>>>(feat, W, b, h, edst, ghist,
                                              n_nodes, n_edges, nb);
        coarse_scan<<<1, 256, 0, stream>>>(ghist, goff, gcur, nb);
        stage_kernel<<<(n_edges + SE_PER_BLK - 1) / SE_PER_BLK, 256, 0, stream>>>(
            esrc, edst, ew, gcur, gstage, n_edges, nb);
        bin_sort<<<nb, 256, 0, stream>>>(gstage, goff, gcur, seg, n_nodes, nb);
        gather_kernel<<<((size_t)n_nodes * 64 + 255) / 256, 256, 0, stream>>>(
            h, seg, gstage, out, n_nodes);
    } else {
        // fallback: plain linear (hist pointer unused -> pass ghist=nullptr-safe
        // via a dummy region) then atomic scatter
        int* dummy = (int*)(wsb + off_ghist);
        hipMemsetAsync(dummy, 0, (size_t)nb * sizeof(int), stream);
        linear_hist<<<nlin, 256, 0, stream>>>(feat, W, b, h, edst, dummy,
                                              n_nodes, n_edges, nb);
        hipMemsetAsync(d_out, 0, (size_t)out_size * sizeof(float), stream);
        scatter_kernel<<<8192, 256, 0, stream>>>(h, esrc, edst, ew, out, n_edges);
    }
}

// Round 8
// 179.210 us; speedup vs baseline: 1.6347x; 1.6347x over previous
//
#include <hip/hip_runtime.h>

#define IN_FEATS 128
#define OUT_FEATS 64
#define TM 64              // rows per linear block
#define FS_LD 132          // padded LDS leading dim
#define BW_LOG 6           // bucket width = 64 nodes
#define BWIDTH 64
#define MAX_NB 1024
#define SE_PER_BLK 4096    // edges staged per block (256 thr x 16)
#define MAX_BUCKET 3072    // records per bucket in bin_sort LDS (24 KB)

__device__ inline void fma4(float4& a, float s, const float4& v) {
    a.x += s * v.x; a.y += s * v.y; a.z += s * v.z; a.w += s * v.w;
}
__device__ inline unsigned short f2bf(float f) {   // RTNE fp32 -> bf16
    unsigned u = __float_as_uint(f);
    u += 0x7FFFu + ((u >> 16) & 1u);
    return (unsigned short)(u >> 16);
}
__device__ inline float bf2f(unsigned short v) {
    return __uint_as_float(((unsigned)v) << 16);
}

// ------- Linear (h = bf16(feat@W^T+b), feature-split halves) + coarse hist ---
__global__ __launch_bounds__(256) void linear_hist(
    const float* __restrict__ feat, const float* __restrict__ W,
    const float* __restrict__ b, unsigned short* __restrict__ h0,
    unsigned short* __restrict__ h1,
    const int* __restrict__ edst, int* __restrict__ ghist,
    int n_nodes, int n_edges, int nb)
{
    __shared__ float fs[TM * FS_LD];
    __shared__ float wt[IN_FEATS * OUT_FEATS];
    __shared__ int hist[MAX_NB];
    const int tid  = threadIdx.x;
    const int row0 = blockIdx.x * TM;

    for (int i = tid; i < nb; i += 256) hist[i] = 0;
    __syncthreads();

    {   // stage Wt
        const int c  = tid & 63;
        const int kb = (tid >> 6) * 32;
        const float4* wrow = (const float4*)(W + (size_t)c * IN_FEATS + kb);
#pragma unroll
        for (int i = 0; i < 8; ++i) {
            float4 t = wrow[i];
            int k = kb + i * 4;
            wt[(k + 0) * OUT_FEATS + c] = t.x;
            wt[(k + 1) * OUT_FEATS + c] = t.y;
            wt[(k + 2) * OUT_FEATS + c] = t.z;
            wt[(k + 3) * OUT_FEATS + c] = t.w;
        }
    }
    {   // stage feat tile
#pragma unroll
        for (int i = 0; i < 8; ++i) {
            int flat = i * 256 + tid;
            int r  = flat >> 5;
            int kc = flat & 31;
            int gr = row0 + r;
            float4 t = (gr < n_nodes)
                ? ((const float4*)(feat + (size_t)gr * IN_FEATS))[kc]
                : make_float4(0.f, 0.f, 0.f, 0.f);
            *((float4*)&fs[r * FS_LD + kc * 4]) = t;
        }
    }
    {   // fused histogram (overlaps FMA work)
        const int n4 = n_edges >> 2;
        const int4* ed4 = (const int4*)edst;
        for (int i = blockIdx.x * 256 + tid; i < n4; i += gridDim.x * 256) {
            int4 d = ed4[i];
            atomicAdd(&hist[d.x >> BW_LOG], 1);
            atomicAdd(&hist[d.y >> BW_LOG], 1);
            atomicAdd(&hist[d.z >> BW_LOG], 1);
            atomicAdd(&hist[d.w >> BW_LOG], 1);
        }
        if (blockIdx.x == 0 && tid < (n_edges & 3))
            atomicAdd(&hist[edst[n4 * 4 + tid] >> BW_LOG], 1);
    }
    __syncthreads();
    for (int i = tid; i < nb; i += 256)
        if (hist[i]) atomicAdd(&ghist[i], hist[i]);

    const int tx = tid & 15;
    const int ty = tid >> 4;

    float4 acc[4];
#pragma unroll
    for (int i = 0; i < 4; ++i) acc[i] = make_float4(0.f, 0.f, 0.f, 0.f);

    for (int k = 0; k < IN_FEATS; k += 4) {
        float4 fv[4], wv[4];
#pragma unroll
        for (int i = 0; i < 4; ++i)
            fv[i] = *((const float4*)&fs[(ty * 4 + i) * FS_LD + k]);
#pragma unroll
        for (int j = 0; j < 4; ++j)
            wv[j] = *((const float4*)&wt[(k + j) * OUT_FEATS + tx * 4]);
#pragma unroll
        for (int i = 0; i < 4; ++i) {
            fma4(acc[i], fv[i].x, wv[0]);
            fma4(acc[i], fv[i].y, wv[1]);
            fma4(acc[i], fv[i].z, wv[2]);
            fma4(acc[i], fv[i].w, wv[3]);
        }
    }

    float4 b4 = ((const float4*)b)[tx];
    const int c0 = tx * 4;                       // output col group
    unsigned short* hp = (c0 < 32) ? h0 : h1;    // feature-split table
    const int cc = c0 & 31;
#pragma unroll
    for (int i = 0; i < 4; ++i) {
        int r = row0 + ty * 4 + i;
        if (r < n_nodes) {
            float4 o = acc[i];
            o.x += b4.x; o.y += b4.y; o.z += b4.z; o.w += b4.w;
            ushort4 s4;
            s4.x = f2bf(o.x); s4.y = f2bf(o.y);
            s4.z = f2bf(o.z); s4.w = f2bf(o.w);
            *((ushort4*)&hp[(size_t)r * 32 + cc]) = s4;
        }
    }
}

// ------- Scan over bucket counts (exact, no slack) -------
__global__ __launch_bounds__(256) void coarse_scan(
    const int* __restrict__ ghist, int* __restrict__ goff,
    int* __restrict__ gcur, int nb)
{
    __shared__ int wsum[4];
    __shared__ int wpre[4];
    const int tid  = threadIdx.x;
    const int lane = tid & 63;
    const int wv   = tid >> 6;
    int i0 = tid * 4;
    int v[4];
    int s = 0;
#pragma unroll
    for (int j = 0; j < 4; ++j) v[j] = (i0 + j < nb) ? ghist[i0 + j] : 0;
#pragma unroll
    for (int j = 0; j < 4; ++j) { int t = v[j]; v[j] = s; s += t; }
    int inc = s;
    for (int off = 1; off < 64; off <<= 1) {
        int t = __shfl_up(inc, off, 64);
        if (lane >= off) inc += t;
    }
    int wexcl = inc - s;
    if (lane == 63) wsum[wv] = inc;
    __syncthreads();
    if (tid == 0) {
        int a = 0;
        for (int k = 0; k < 4; ++k) { wpre[k] = a; a += wsum[k]; }
    }
    __syncthreads();
    int tbase = wpre[wv] + wexcl;
#pragma unroll
    for (int j = 0; j < 4; ++j) {
        int idx = i0 + j;
        if (idx < nb) { int e = tbase + v[j]; goff[idx] = e; gcur[idx] = e; }
    }
    if (tid == 0) goff[nb] = wpre[3] + wsum[3];
}

// ------- Stage: bin edges by coarse bucket (exact allocation) -------
// Record: int2{ (dst&63)<<16 | src , bits(weight) }
__global__ __launch_bounds__(256) void stage_kernel(
    const int* __restrict__ esrc, const int* __restrict__ edst,
    const float* __restrict__ ew, int* __restrict__ gcur,
    int2* __restrict__ gstage, int n_edges, int nb)
{
    __shared__ int cnt[MAX_NB];
    __shared__ int base[MAX_NB];
    const int tid = threadIdx.x;
    const int e0  = blockIdx.x * SE_PER_BLK;

    for (int i = tid; i < nb; i += 256) cnt[i] = 0;
    __syncthreads();

    int key[16]; float w[16]; int bk[16]; int rk[16];
#pragma unroll
    for (int i = 0; i < 16; ++i) {
        int e = e0 + i * 256 + tid;
        if (e < n_edges) {
            int d = edst[e];
            int b = d >> BW_LOG;
            bk[i]  = b;
            key[i] = ((d & (BWIDTH - 1)) << 16) | esrc[e];
            w[i]   = ew[e];
            rk[i]  = atomicAdd(&cnt[b], 1);
        } else bk[i] = -1;
    }
    __syncthreads();
    for (int i = tid; i < nb; i += 256) {
        int c = cnt[i];
        base[i] = c ? atomicAdd(&gcur[i], c) : 0;
    }
    __syncthreads();
#pragma unroll
    for (int i = 0; i < 16; ++i) {
        if (bk[i] >= 0)
            gstage[base[bk[i]] + rk[i]] = make_int2(key[i], __float_as_int(w[i]));
    }
}

// ------- Bin-sort: bucket -> per-node (start,end) segments, in place -------
__global__ __launch_bounds__(256) void bin_sort(
    int2* __restrict__ gstage, const int* __restrict__ goff,
    int2* __restrict__ seg, int n_nodes, int nb)
{
    __shared__ int2 recs[MAX_BUCKET];
    __shared__ int cnt[BWIDTH];
    __shared__ int cur[BWIDTH];
    const int tid = threadIdx.x;
    const int b   = blockIdx.x;
    const int s0  = goff[b], s1 = goff[b + 1];
    const int m   = s1 - s0;

    if (tid < BWIDTH) cnt[tid] = 0;
    __syncthreads();

    for (int i = tid; i < m; i += 256) {
        int2 r = gstage[s0 + i];
        recs[i] = r;
        atomicAdd(&cnt[(r.x >> 16) & 63], 1);
    }
    __syncthreads();

    if (tid < 64) {
        int v = cnt[tid];
        int inc = v;
        for (int o = 1; o < 64; o <<= 1) {
            int t = __shfl_up(inc, o, 64);
            if (tid >= o) inc += t;
        }
        int excl = inc - v;
        cur[tid] = excl;
        int node = b * BWIDTH + tid;
        if (node < n_nodes) seg[node] = make_int2(s0 + excl, s0 + excl + v);
    }
    __syncthreads();

    for (int i = tid; i < m; i += 256) {
        int2 r = recs[i];
        int pos = atomicAdd(&cur[(r.x >> 16) & 63], 1);
        gstage[s0 + pos] = r;
    }
}

// ------- Gather over ONE feature-half table (3.2 MB -> L2-resident) -------
// 2 nodes per wave: lanes 0-31 node A, lanes 32-63 node B; lane = feature.
// Half h-row = 32 bf16 = 64 B = one cache line.
__global__ __launch_bounds__(256) void gather_half(
    const unsigned short* __restrict__ hp, const int2* __restrict__ seg,
    const int2* __restrict__ perm2, float* __restrict__ out,
    int n_nodes, int half)
{
    const int wid  = (blockIdx.x * blockDim.x + threadIdx.x) >> 6;
    const int lane = threadIdx.x & 63;
    const int g    = lane >> 5;
    const int f    = lane & 31;
    const int node = wid * 2 + g;

    int2 se = (node < n_nodes) ? seg[node] : make_int2(0, 0);
    const int len = se.y - se.x;
    const int omax = max(len, __shfl_xor(len, 32, 64));

    float acc = 0.f;
    for (int u = 0; u < omax; u += 8) {
        int2 r[8]; float hv[8];
#pragma unroll
        for (int k = 0; k < 8; ++k) {
            int uk  = u + k;
            int pos = (uk < len) ? (se.x + uk) : (len > 0 ? se.y - 1 : 0);
            r[k] = perm2[pos];
        }
#pragma unroll
        for (int k = 0; k < 8; ++k)
            hv[k] = bf2f(hp[(size_t)(r[k].x & 0xFFFF) * 32 + f]);
#pragma unroll
        for (int k = 0; k < 8; ++k) {
            float w = (u + k < len) ? __int_as_float(r[k].y) : 0.f;
            acc += w * hv[k];
        }
    }
    if (node < n_nodes)
        out[(size_t)node * OUT_FEATS + half * 32 + f] = acc;
}

// ------- Fallback atomic scatter -------
__global__ __launch_bounds__(256) void scatter_kernel(
    const unsigned short* __restrict__ h0, const unsigned short* __restrict__ h1,
    const int* __restrict__ esrc, const int* __restrict__ edst,
    const float* __restrict__ ew, float* __restrict__ out, int n_edges)
{
    const int lane = threadIdx.x & 63;
    const int wave = threadIdx.x >> 6;
    const int stride = gridDim.x * 4;
    const unsigned short* hp = (lane < 32) ? h0 : h1;
    for (int e = blockIdx.x * 4 + wave; e < n_edges; e += stride) {
        const int s = esrc[e];
        const int d = edst[e];
        const float w = ew[e];
        atomicAdd(out + (size_t)d * OUT_FEATS + lane,
                  bf2f(hp[(size_t)s * 32 + (lane & 31)]) * w);
    }
}

extern "C" void kernel_launch(void* const* d_in, const int* in_sizes, int n_in,
                              void* d_out, int out_size, void* d_ws, size_t ws_size,
                              hipStream_t stream) {
    const float* feat = (const float*)d_in[0];
    const int*   esrc = (const int*)d_in[1];
    const int*   edst = (const int*)d_in[2];
    const float* ew   = (const float*)d_in[3];
    const float* W    = (const float*)d_in[4];
    const float* b    = (const float*)d_in[5];
    float* out = (float*)d_out;

    const int n_nodes = in_sizes[0] / IN_FEATS;  // 50000
    const int n_edges = in_sizes[1];             // 800000
    const int nb = (n_nodes + BWIDTH - 1) >> BW_LOG;  // 782
    const int nlin = (n_nodes + TM - 1) / TM;

    // ws: h0 | h1 (each n*32 bf16) | ghist(nb) | goff(nb+1) | gcur(nb)
    //     | seg(n int2) | gstage(E int2)
    char* wsb = (char*)d_ws;
    unsigned short* h0 = (unsigned short*)wsb;
    unsigned short* h1 = h0 + (size_t)n_nodes * 32;
    size_t off_ghist = (((size_t)n_nodes * 64 * sizeof(unsigned short)) + 15) & ~(size_t)15;
    size_t sz_ghist  = (((size_t)nb * sizeof(int)) + 15) & ~(size_t)15;
    size_t off_goff  = off_ghist + sz_ghist;
    size_t sz_goff   = (((size_t)(nb + 1) * sizeof(int)) + 15) & ~(size_t)15;
    size_t off_gcur  = off_goff + sz_goff;
    size_t sz_gcur   = (((size_t)nb * sizeof(int)) + 15) & ~(size_t)15;
    size_t off_seg   = off_gcur + sz_gcur;
    size_t sz_seg    = (((size_t)n_nodes * sizeof(int2)) + 15) & ~(size_t)15;
    size_t off_stage = off_seg + sz_seg;
    size_t needed    = off_stage + (size_t)n_edges * sizeof(int2);

    bool binnable = (nb <= MAX_NB) && (n_nodes < 65536) &&
                    ((size_t)n_edges / (size_t)nb * 2 + 256 <= MAX_BUCKET);

    if (ws_size >= needed && binnable) {
        int*  ghist  = (int*)(wsb + off_ghist);
        int*  goff   = (int*)(wsb + off_goff);
        int*  gcur   = (int*)(wsb + off_gcur);
        int2* seg    = (int2*)(wsb + off_seg);
        int2* gstage = (int2*)(wsb + off_stage);
        hipMemsetAsync(ghist, 0, (size_t)nb * sizeof(int), stream);
        linear_hist<<<nlin, 256, 0, stream>>>(feat, W, b, h0, h1, edst, ghist,
                                              n_nodes, n_edges, nb);
        coarse_scan<<<1, 256, 0, stream>>>(ghist, goff, gcur, nb);
        stage_kernel<<<(n_edges + SE_PER_BLK - 1) / SE_PER_BLK, 256, 0, stream>>>(
            esrc, edst, ew, gcur, gstage, n_edges, nb);
        bin_sort<<<nb, 256, 0, stream>>>(gstage, goff, seg, n_nodes, nb);
        const int gwaves  = (n_nodes + 1) / 2;
        const int gblocks = (gwaves + 3) / 4;
        gather_half<<<gblocks, 256, 0, stream>>>(h0, seg, gstage, out, n_nodes, 0);
        gather_half<<<gblocks, 256, 0, stream>>>(h1, seg, gstage, out, n_nodes, 1);
    } else {
        int* dummy = (int*)(wsb + off_ghist);
        hipMemsetAsync(dummy, 0, (size_t)nb * sizeof(int), stream);
        linear_hist<<<nlin, 256, 0, stream>>>(feat, W, b, h0, h1, edst, dummy,
                                              n_nodes, n_edges, nb);
        hipMemsetAsync(d_out, 0, (size_t)out_size * sizeof(float), stream);
        scatter_kernel<<<8192, 256, 0, stream>>>(h0, h1, esrc, edst, ew, out, n_edges);
    }
}

// Round 9
// 177.420 us; speedup vs baseline: 1.6512x; 1.0101x over previous
//
#include <hip/hip_runtime.h>

#define IN_FEATS 128
#define OUT_FEATS 64
#define TM 64              // rows per linear block
#define FS_LD 132          // padded LDS leading dim
#define BW_LOG 6           // bucket width = 64 nodes
#define BWIDTH 64
#define MAX_NB 1024
#define SE_PER_BLK 8192    // edges per stage block (two-pass)
#define MAX_BUCKET 3072    // records per bucket in bin_sort LDS (24 KB)

__device__ inline void fma4(float4& a, float s, const float4& v) {
    a.x += s * v.x; a.y += s * v.y; a.z += s * v.z; a.w += s * v.w;
}
__device__ inline unsigned short f2bf(float f) {   // RTNE fp32 -> bf16
    unsigned u = __float_as_uint(f);
    u += 0x7FFFu + ((u >> 16) & 1u);
    return (unsigned short)(u >> 16);
}
__device__ inline float bf2f_lo(unsigned v) {
    return __uint_as_float(v << 16);
}
__device__ inline float bf2f_hi(unsigned v) {
    return __uint_as_float(v & 0xFFFF0000u);
}

// ------- Linear (h = bf16(feat@W^T+b)) fused with coarse dst-histogram -------
__global__ __launch_bounds__(256) void linear_hist(
    const float* __restrict__ feat, const float* __restrict__ W,
    const float* __restrict__ b, unsigned short* __restrict__ h,
    const int* __restrict__ edst, int* __restrict__ ghist,
    int n_nodes, int n_edges, int nb)
{
    __shared__ float fs[TM * FS_LD];
    __shared__ float wt[IN_FEATS * OUT_FEATS];
    __shared__ int hist[MAX_NB];
    const int tid  = threadIdx.x;
    const int row0 = blockIdx.x * TM;

    for (int i = tid; i < nb; i += 256) hist[i] = 0;
    __syncthreads();

    {   // stage Wt
        const int c  = tid & 63;
        const int kb = (tid >> 6) * 32;
        const float4* wrow = (const float4*)(W + (size_t)c * IN_FEATS + kb);
#pragma unroll
        for (int i = 0; i < 8; ++i) {
            float4 t = wrow[i];
            int k = kb + i * 4;
            wt[(k + 0) * OUT_FEATS + c] = t.x;
            wt[(k + 1) * OUT_FEATS + c] = t.y;
            wt[(k + 2) * OUT_FEATS + c] = t.z;
            wt[(k + 3) * OUT_FEATS + c] = t.w;
        }
    }
    {   // stage feat tile
#pragma unroll
        for (int i = 0; i < 8; ++i) {
            int flat = i * 256 + tid;
            int r  = flat >> 5;
            int kc = flat & 31;
            int gr = row0 + r;
            float4 t = (gr < n_nodes)
                ? ((const float4*)(feat + (size_t)gr * IN_FEATS))[kc]
                : make_float4(0.f, 0.f, 0.f, 0.f);
            *((float4*)&fs[r * FS_LD + kc * 4]) = t;
        }
    }
    {   // fused histogram (overlaps FMA work)
        const int n4 = n_edges >> 2;
        const int4* ed4 = (const int4*)edst;
        for (int i = blockIdx.x * 256 + tid; i < n4; i += gridDim.x * 256) {
            int4 d = ed4[i];
            atomicAdd(&hist[d.x >> BW_LOG], 1);
            atomicAdd(&hist[d.y >> BW_LOG], 1);
            atomicAdd(&hist[d.z >> BW_LOG], 1);
            atomicAdd(&hist[d.w >> BW_LOG], 1);
        }
        if (blockIdx.x == 0 && tid < (n_edges & 3))
            atomicAdd(&hist[edst[n4 * 4 + tid] >> BW_LOG], 1);
    }
    __syncthreads();
    for (int i = tid; i < nb; i += 256)
        if (hist[i]) atomicAdd(&ghist[i], hist[i]);

    const int tx = tid & 15;
    const int ty = tid >> 4;

    float4 acc[4];
#pragma unroll
    for (int i = 0; i < 4; ++i) acc[i] = make_float4(0.f, 0.f, 0.f, 0.f);

    for (int k = 0; k < IN_FEATS; k += 4) {
        float4 fv[4], wv[4];
#pragma unroll
        for (int i = 0; i < 4; ++i)
            fv[i] = *((const float4*)&fs[(ty * 4 + i) * FS_LD + k]);
#pragma unroll
        for (int j = 0; j < 4; ++j)
            wv[j] = *((const float4*)&wt[(k + j) * OUT_FEATS + tx * 4]);
#pragma unroll
        for (int i = 0; i < 4; ++i) {
            fma4(acc[i], fv[i].x, wv[0]);
            fma4(acc[i], fv[i].y, wv[1]);
            fma4(acc[i], fv[i].z, wv[2]);
            fma4(acc[i], fv[i].w, wv[3]);
        }
    }

    float4 b4 = ((const float4*)b)[tx];
#pragma unroll
    for (int i = 0; i < 4; ++i) {
        int r = row0 + ty * 4 + i;
        if (r < n_nodes) {
            float4 o = acc[i];
            o.x += b4.x; o.y += b4.y; o.z += b4.z; o.w += b4.w;
            ushort4 s4;
            s4.x = f2bf(o.x); s4.y = f2bf(o.y);
            s4.z = f2bf(o.z); s4.w = f2bf(o.w);
            *((ushort4*)&h[(size_t)r * OUT_FEATS + tx * 4]) = s4;
        }
    }
}

// ------- Scan over bucket counts (exact) -------
__global__ __launch_bounds__(256) void coarse_scan(
    const int* __restrict__ ghist, int* __restrict__ goff,
    int* __restrict__ gcur, int nb)
{
    __shared__ int wsum[4];
    __shared__ int wpre[4];
    const int tid  = threadIdx.x;
    const int lane = tid & 63;
    const int wv   = tid >> 6;
    int i0 = tid * 4;
    int v[4];
    int s = 0;
#pragma unroll
    for (int j = 0; j < 4; ++j) v[j] = (i0 + j < nb) ? ghist[i0 + j] : 0;
#pragma unroll
    for (int j = 0; j < 4; ++j) { int t = v[j]; v[j] = s; s += t; }
    int inc = s;
    for (int off = 1; off < 64; off <<= 1) {
        int t = __shfl_up(inc, off, 64);
        if (lane >= off) inc += t;
    }
    int wexcl = inc - s;
    if (lane == 63) wsum[wv] = inc;
    __syncthreads();
    if (tid == 0) {
        int a = 0;
        for (int k = 0; k < 4; ++k) { wpre[k] = a; a += wsum[k]; }
    }
    __syncthreads();
    int tbase = wpre[wv] + wexcl;
#pragma unroll
    for (int j = 0; j < 4; ++j) {
        int idx = i0 + j;
        if (idx < nb) { int e = tbase + v[j]; goff[idx] = e; gcur[idx] = e; }
    }
    if (tid == 0) goff[nb] = wpre[3] + wsum[3];
}

// ------- Stage: two-pass (count / alloc / rank+write), 8192 edges/block -----
// Record: int2{ (dst&63)<<16 | src , bits(weight) }
__global__ __launch_bounds__(256) void stage_kernel(
    const int* __restrict__ esrc, const int* __restrict__ edst,
    const float* __restrict__ ew, int* __restrict__ gcur,
    int2* __restrict__ gstage, int n_edges, int nb)
{
    __shared__ int cntA[MAX_NB];
    __shared__ int cntB[MAX_NB];
    __shared__ int base[MAX_NB];
    const int tid = threadIdx.x;
    const int e0  = blockIdx.x * SE_PER_BLK;
    const int e1  = min(e0 + SE_PER_BLK, n_edges);

    for (int i = tid; i < nb; i += 256) { cntA[i] = 0; cntB[i] = 0; }
    __syncthreads();

    // pass A: count buckets (edst chunk lands in L2 for pass B)
    for (int e = e0 + tid; e < e1; e += 256)
        atomicAdd(&cntA[edst[e] >> BW_LOG], 1);
    __syncthreads();

    // alloc contiguous runs per bucket
    for (int i = tid; i < nb; i += 256) {
        int c = cntA[i];
        base[i] = c ? atomicAdd(&gcur[i], c) : 0;
    }
    __syncthreads();

    // pass B: rank + write (runs of ~10 records -> mostly full lines)
    for (int e = e0 + tid; e < e1; e += 256) {
        int d  = edst[e];
        int b  = d >> BW_LOG;
        int rk = atomicAdd(&cntB[b], 1);
        gstage[base[b] + rk] =
            make_int2(((d & (BWIDTH - 1)) << 16) | esrc[e],
                      __float_as_int(ew[e]));
    }
}

// ------- Bin-sort: bucket -> per-node (start,end) segments, in place -------
__global__ __launch_bounds__(256) void bin_sort(
    int2* __restrict__ gstage, const int* __restrict__ goff,
    int2* __restrict__ seg, int n_nodes, int nb)
{
    __shared__ int2 recs[MAX_BUCKET];
    __shared__ int cnt[BWIDTH];
    __shared__ int cur[BWIDTH];
    const int tid = threadIdx.x;
    const int b   = blockIdx.x;
    const int s0  = goff[b], s1 = goff[b + 1];
    const int m   = s1 - s0;

    if (tid < BWIDTH) cnt[tid] = 0;
    __syncthreads();

    for (int i = tid; i < m; i += 256) {
        int2 r = gstage[s0 + i];
        recs[i] = r;
        atomicAdd(&cnt[(r.x >> 16) & 63], 1);
    }
    __syncthreads();

    if (tid < 64) {
        int v = cnt[tid];
        int inc = v;
        for (int o = 1; o < 64; o <<= 1) {
            int t = __shfl_up(inc, o, 64);
            if (tid >= o) inc += t;
        }
        int excl = inc - v;
        cur[tid] = excl;
        int node = b * BWIDTH + tid;
        if (node < n_nodes) seg[node] = make_int2(s0 + excl, s0 + excl + v);
    }
    __syncthreads();

    for (int i = tid; i < m; i += 256) {
        int2 r = recs[i];
        int pos = atomicAdd(&cur[(r.x >> 16) & 63], 1);
        gstage[s0 + pos] = r;
    }
}

// ------- Gather: 2 nodes per wave, packed-bf16 uint loads -------
// Lane f2 = lane&31 covers feats {2f2, 2f2+1}; 32 lanes x 4B = full 128B row.
__global__ __launch_bounds__(256) void gather_kernel(
    const unsigned short* __restrict__ h, const int2* __restrict__ seg,
    const int2* __restrict__ perm2, float* __restrict__ out, int n_nodes)
{
    const int wid  = (blockIdx.x * blockDim.x + threadIdx.x) >> 6;
    const int lane = threadIdx.x & 63;
    const int g    = lane >> 5;
    const int f2   = lane & 31;
    const int node = wid * 2 + g;
    const unsigned* h32 = (const unsigned*)h;

    int2 se = (node < n_nodes) ? seg[node] : make_int2(0, 0);
    const int len = se.y - se.x;
    const int olen = __shfl_xor(len, 32, 64);
    const int omax = max(len, olen);

    float a0 = 0.f, a1 = 0.f;
    for (int u = 0; u < omax; u += 8) {
        int2 r[8]; unsigned hv[8];
#pragma unroll
        for (int k = 0; k < 8; ++k) {
            int uk  = u + k;
            int pos = (uk < len) ? (se.x + uk) : (len > 0 ? se.y - 1 : 0);
            r[k] = perm2[pos];
        }
#pragma unroll
        for (int k = 0; k < 8; ++k)
            hv[k] = h32[(size_t)(r[k].x & 0xFFFF) * 32 + f2];
#pragma unroll
        for (int k = 0; k < 8; ++k) {
            float w = (u + k < len) ? __int_as_float(r[k].y) : 0.f;
            a0 += w * bf2f_lo(hv[k]);
            a1 += w * bf2f_hi(hv[k]);
        }
    }
    if (node < n_nodes) {
        float2 o; o.x = a0; o.y = a1;
        *((float2*)&out[(size_t)node * OUT_FEATS + 2 * f2]) = o;
    }
}

// ------- Fallback atomic scatter -------
__global__ __launch_bounds__(256) void scatter_kernel(
    const unsigned short* __restrict__ h, const int* __restrict__ esrc,
    const int* __restrict__ edst, const float* __restrict__ ew,
    float* __restrict__ out, int n_edges)
{
    const int lane = threadIdx.x & 63;
    const int wave = threadIdx.x >> 6;
    const int stride = gridDim.x * 4;
    for (int e = blockIdx.x * 4 + wave; e < n_edges; e += stride) {
        const int s = esrc[e];
        const int d = edst[e];
        const float w = ew[e];
        atomicAdd(out + (size_t)d * OUT_FEATS + lane,
                  bf2f_lo((unsigned)h[(size_t)s * OUT_FEATS + lane]) * w);
    }
}

extern "C" void kernel_launch(void* const* d_in, const int* in_sizes, int n_in,
                              void* d_out, int out_size, void* d_ws, size_t ws_size,
                              hipStream_t stream) {
    const float* feat = (const float*)d_in[0];
    const int*   esrc = (const int*)d_in[1];
    const int*   edst = (const int*)d_in[2];
    const float* ew   = (const float*)d_in[3];
    const float* W    = (const float*)d_in[4];
    const float* b    = (const float*)d_in[5];
    float* out = (float*)d_out;

    const int n_nodes = in_sizes[0] / IN_FEATS;  // 50000
    const int n_edges = in_sizes[1];             // 800000
    const int nb = (n_nodes + BWIDTH - 1) >> BW_LOG;  // 782
    const int nlin = (n_nodes + TM - 1) / TM;

    // ws: h(bf16 n*64) | ghist(nb) | goff(nb+1) | gcur(nb) | seg(n int2) | gstage
    char* wsb = (char*)d_ws;
    unsigned short* h = (unsigned short*)wsb;
    size_t off_ghist = (((size_t)n_nodes * OUT_FEATS * sizeof(unsigned short)) + 15) & ~(size_t)15;
    size_t sz_ghist  = (((size_t)nb * sizeof(int)) + 15) & ~(size_t)15;
    size_t off_goff  = off_ghist + sz_ghist;
    size_t sz_goff   = (((size_t)(nb + 1) * sizeof(int)) + 15) & ~(size_t)15;
    size_t off_gcur  = off_goff + sz_goff;
    size_t sz_gcur   = (((size_t)nb * sizeof(int)) + 15) & ~(size_t)15;
    size_t off_seg   = off_gcur + sz_gcur;
    size_t sz_seg    = (((size_t)n_nodes * sizeof(int2)) + 15) & ~(size_t)15;
    size_t off_stage = off_seg + sz_seg;
    size_t needed    = off_stage + (size_t)n_edges * sizeof(int2);

    bool binnable = (nb <= MAX_NB) && (n_nodes < 65536) &&
                    ((size_t)n_edges / (size_t)nb * 2 + 256 <= MAX_BUCKET);

    if (ws_size >= needed && binnable) {
        int*  ghist  = (int*)(wsb + off_ghist);
        int*  goff   = (int*)(wsb + off_goff);
        int*  gcur   = (int*)(wsb + off_gcur);
        int2* seg    = (int2*)(wsb + off_seg);
        int2* gstage = (int2*)(wsb + off_stage);
        hipMemsetAsync(ghist, 0, (size_t)nb * sizeof(int), stream);
        linear_hist<<<nlin, 256, 0, stream>>>(feat, W, b, h, edst, ghist,
                                              n_nodes, n_edges, nb);
        coarse_scan<<<1, 256, 0, stream>>>(ghist, goff, gcur, nb);
        stage_kernel<<<(n_edges + SE_PER_BLK - 1) / SE_PER_BLK, 256, 0, stream>>>(
            esrc, edst, ew, gcur, gstage, n_edges, nb);
        bin_sort<<<nb, 256, 0, stream>>>(gstage, goff, seg, n_nodes, nb);
        const int gwaves  = (n_nodes + 1) / 2;
        gather_kernel<<<(gwaves + 3) / 4, 256, 0, stream>>>(
            h, seg, gstage, out, n_nodes);
    } else {
        int* dummy = (int*)(wsb + off_ghist);
        hipMemsetAsync(dummy, 0, (size_t)nb * sizeof(int), stream);
        linear_hist<<<nlin, 256, 0, stream>>>(feat, W, b, h, edst, dummy,
                                              n_nodes, n_edges, nb);
        hipMemsetAsync(d_out, 0, (size_t)out_size * sizeof(float), stream);
        scatter_kernel<<<8192, 256, 0, stream>>>(h, esrc, edst, ew, out, n_edges);
    }
}

// Round 10
// 153.541 us; speedup vs baseline: 1.9080x; 1.1555x over previous
//
#include <hip/hip_runtime.h>

#define IN_FEATS 128
#define OUT_FEATS 64
#define TM 64              // rows per linear block
#define FS_LD 132          // padded LDS leading dim
#define BW_LOG 6           // bucket width = 64 nodes
#define BWIDTH 64
#define MAX_NB 1024
#define SE_PER_BLK 8192    // edges per stage block (two-pass)
#define MAX_BUCKET 3072    // records per bucket in bin_sort LDS (24 KB)

__device__ inline void fma4(float4& a, float s, const float4& v) {
    a.x += s * v.x; a.y += s * v.y; a.z += s * v.z; a.w += s * v.w;
}
__device__ inline unsigned short f2bf(float f) {   // RTNE fp32 -> bf16
    unsigned u = __float_as_uint(f);
    u += 0x7FFFu + ((u >> 16) & 1u);
    return (unsigned short)(u >> 16);
}
__device__ inline float bf2f_lo(unsigned v) { return __uint_as_float(v << 16); }
__device__ inline float bf2f_hi(unsigned v) { return __uint_as_float(v & 0xFFFF0000u); }

// ------- Coarse histogram over dst>>6 (separate kernel: its merge is only
//         128 x nb atomics, not 782 x nb) -------
__global__ __launch_bounds__(256) void coarse_hist(
    const int* __restrict__ edst, int* __restrict__ ghist, int n_edges, int nb)
{
    __shared__ int hist[MAX_NB];
    const int tid = threadIdx.x;
    for (int i = tid; i < nb; i += 256) hist[i] = 0;
    __syncthreads();

    const int n4 = n_edges >> 2;
    const int4* ed4 = (const int4*)edst;
    for (int i = blockIdx.x * 256 + tid; i < n4; i += gridDim.x * 256) {
        int4 d = ed4[i];
        atomicAdd(&hist[d.x >> BW_LOG], 1);
        atomicAdd(&hist[d.y >> BW_LOG], 1);
        atomicAdd(&hist[d.z >> BW_LOG], 1);
        atomicAdd(&hist[d.w >> BW_LOG], 1);
    }
    if (blockIdx.x == 0 && tid < (n_edges & 3))
        atomicAdd(&hist[edst[n4 * 4 + tid] >> BW_LOG], 1);
    __syncthreads();
    for (int i = tid; i < nb; i += 256)
        if (hist[i]) atomicAdd(&ghist[i], hist[i]);
}

// ------- Scan over bucket counts (exact) -------
__global__ __launch_bounds__(256) void coarse_scan(
    const int* __restrict__ ghist, int* __restrict__ goff,
    int* __restrict__ gcur, int nb)
{
    __shared__ int wsum[4];
    __shared__ int wpre[4];
    const int tid  = threadIdx.x;
    const int lane = tid & 63;
    const int wv   = tid >> 6;
    int i0 = tid * 4;
    int v[4];
    int s = 0;
#pragma unroll
    for (int j = 0; j < 4; ++j) v[j] = (i0 + j < nb) ? ghist[i0 + j] : 0;
#pragma unroll
    for (int j = 0; j < 4; ++j) { int t = v[j]; v[j] = s; s += t; }
    int inc = s;
    for (int off = 1; off < 64; off <<= 1) {
        int t = __shfl_up(inc, off, 64);
        if (lane >= off) inc += t;
    }
    int wexcl = inc - s;
    if (lane == 63) wsum[wv] = inc;
    __syncthreads();
    if (tid == 0) {
        int a = 0;
        for (int k = 0; k < 4; ++k) { wpre[k] = a; a += wsum[k]; }
    }
    __syncthreads();
    int tbase = wpre[wv] + wexcl;
#pragma unroll
    for (int j = 0; j < 4; ++j) {
        int idx = i0 + j;
        if (idx < nb) { int e = tbase + v[j]; goff[idx] = e; gcur[idx] = e; }
    }
    if (tid == 0) goff[nb] = wpre[3] + wsum[3];
}

// ------- Fused stage + linear: role-split by blockIdx -------
// Blocks [0,nstage): two-pass edge binning (memory/atomic-bound).
// Blocks [nstage, nstage+nlin): GEMM h = bf16(feat@W^T+b) (VALU/LDS-bound).
// Independent work on disjoint pipes -> co-scheduled, time ~ max not sum.
__global__ __launch_bounds__(256) void stage_linear(
    const float* __restrict__ feat, const float* __restrict__ W,
    const float* __restrict__ b, unsigned short* __restrict__ h,
    const int* __restrict__ esrc, const int* __restrict__ edst,
    const float* __restrict__ ew, int* __restrict__ gcur,
    int2* __restrict__ gstage, int n_nodes, int n_edges, int nb, int nstage)
{
    __shared__ union {
        struct { float fs[TM * FS_LD]; float wt[IN_FEATS * OUT_FEATS]; } lin;
        struct { int cntA[MAX_NB]; int cntB[MAX_NB]; int base[MAX_NB]; } st;
    } sm;
    const int tid = threadIdx.x;

    if ((int)blockIdx.x < nstage) {
        // ---------------- stage role ----------------
        int* cntA = sm.st.cntA;
        int* cntB = sm.st.cntB;
        int* base = sm.st.base;
        const int e0 = blockIdx.x * SE_PER_BLK;
        const int e1 = min(e0 + SE_PER_BLK, n_edges);

        for (int i = tid; i < nb; i += 256) { cntA[i] = 0; cntB[i] = 0; }
        __syncthreads();
        for (int e = e0 + tid; e < e1; e += 256)
            atomicAdd(&cntA[edst[e] >> BW_LOG], 1);
        __syncthreads();
        for (int i = tid; i < nb; i += 256) {
            int c = cntA[i];
            base[i] = c ? atomicAdd(&gcur[i], c) : 0;
        }
        __syncthreads();
        for (int e = e0 + tid; e < e1; e += 256) {
            int d  = edst[e];
            int bb = d >> BW_LOG;
            int rk = atomicAdd(&cntB[bb], 1);
            gstage[base[bb] + rk] =
                make_int2(((d & (BWIDTH - 1)) << 16) | esrc[e],
                          __float_as_int(ew[e]));
        }
    } else {
        // ---------------- linear role ----------------
        float* fs = sm.lin.fs;
        float* wt = sm.lin.wt;
        const int row0 = ((int)blockIdx.x - nstage) * TM;

        {   // stage Wt
            const int c  = tid & 63;
            const int kb = (tid >> 6) * 32;
            const float4* wrow = (const float4*)(W + (size_t)c * IN_FEATS + kb);
#pragma unroll
            for (int i = 0; i < 8; ++i) {
                float4 t = wrow[i];
                int k = kb + i * 4;
                wt[(k + 0) * OUT_FEATS + c] = t.x;
                wt[(k + 1) * OUT_FEATS + c] = t.y;
                wt[(k + 2) * OUT_FEATS + c] = t.z;
                wt[(k + 3) * OUT_FEATS + c] = t.w;
            }
        }
        {   // stage feat tile
#pragma unroll
            for (int i = 0; i < 8; ++i) {
                int flat = i * 256 + tid;
                int r  = flat >> 5;
                int kc = flat & 31;
                int gr = row0 + r;
                float4 t = (gr < n_nodes)
                    ? ((const float4*)(feat + (size_t)gr * IN_FEATS))[kc]
                    : make_float4(0.f, 0.f, 0.f, 0.f);
                *((float4*)&fs[r * FS_LD + kc * 4]) = t;
            }
        }
        __syncthreads();

        const int tx = tid & 15;
        const int ty = tid >> 4;

        float4 acc[4];
#pragma unroll
        for (int i = 0; i < 4; ++i) acc[i] = make_float4(0.f, 0.f, 0.f, 0.f);

        for (int k = 0; k < IN_FEATS; k += 4) {
            float4 fv[4], wv[4];
#pragma unroll
            for (int i = 0; i < 4; ++i)
                fv[i] = *((const float4*)&fs[(ty * 4 + i) * FS_LD + k]);
#pragma unroll
            for (int j = 0; j < 4; ++j)
                wv[j] = *((const float4*)&wt[(k + j) * OUT_FEATS + tx * 4]);
#pragma unroll
            for (int i = 0; i < 4; ++i) {
                fma4(acc[i], fv[i].x, wv[0]);
                fma4(acc[i], fv[i].y, wv[1]);
                fma4(acc[i], fv[i].z, wv[2]);
                fma4(acc[i], fv[i].w, wv[3]);
            }
        }

        float4 b4 = ((const float4*)b)[tx];
#pragma unroll
        for (int i = 0; i < 4; ++i) {
            int r = row0 + ty * 4 + i;
            if (r < n_nodes) {
                float4 o = acc[i];
                o.x += b4.x; o.y += b4.y; o.z += b4.z; o.w += b4.w;
                ushort4 s4;
                s4.x = f2bf(o.x); s4.y = f2bf(o.y);
                s4.z = f2bf(o.z); s4.w = f2bf(o.w);
                *((ushort4*)&h[(size_t)r * OUT_FEATS + tx * 4]) = s4;
            }
        }
    }
}

// ------- Bin-sort: bucket -> per-node (start,end) segments, in place -------
__global__ __launch_bounds__(256) void bin_sort(
    int2* __restrict__ gstage, const int* __restrict__ goff,
    int2* __restrict__ seg, int n_nodes, int nb)
{
    __shared__ int2 recs[MAX_BUCKET];
    __shared__ int cnt[BWIDTH];
    __shared__ int cur[BWIDTH];
    const int tid = threadIdx.x;
    const int b   = blockIdx.x;
    const int s0  = goff[b], s1 = goff[b + 1];
    const int m   = s1 - s0;

    if (tid < BWIDTH) cnt[tid] = 0;
    __syncthreads();

    for (int i = tid; i < m; i += 256) {
        int2 r = gstage[s0 + i];
        recs[i] = r;
        atomicAdd(&cnt[(r.x >> 16) & 63], 1);
    }
    __syncthreads();

    if (tid < 64) {
        int v = cnt[tid];
        int inc = v;
        for (int o = 1; o < 64; o <<= 1) {
            int t = __shfl_up(inc, o, 64);
            if (tid >= o) inc += t;
        }
        int excl = inc - v;
        cur[tid] = excl;
        int node = b * BWIDTH + tid;
        if (node < n_nodes) seg[node] = make_int2(s0 + excl, s0 + excl + v);
    }
    __syncthreads();

    for (int i = tid; i < m; i += 256) {
        int2 r = recs[i];
        int pos = atomicAdd(&cur[(r.x >> 16) & 63], 1);
        gstage[s0 + pos] = r;
    }
}

// ------- Gather: 2 nodes per wave, packed-bf16 uint loads -------
__global__ __launch_bounds__(256) void gather_kernel(
    const unsigned short* __restrict__ h, const int2* __restrict__ seg,
    const int2* __restrict__ perm2, float* __restrict__ out, int n_nodes)
{
    const int wid  = (blockIdx.x * blockDim.x + threadIdx.x) >> 6;
    const int lane = threadIdx.x & 63;
    const int g    = lane >> 5;
    const int f2   = lane & 31;
    const int node = wid * 2 + g;
    const unsigned* h32 = (const unsigned*)h;

    int2 se = (node < n_nodes) ? seg[node] : make_int2(0, 0);
    const int len = se.y - se.x;
    const int olen = __shfl_xor(len, 32, 64);
    const int omax = max(len, olen);

    float a0 = 0.f, a1 = 0.f;
    for (int u = 0; u < omax; u += 8) {
        int2 r[8]; unsigned hv[8];
#pragma unroll
        for (int k = 0; k < 8; ++k) {
            int uk  = u + k;
            int pos = (uk < len) ? (se.x + uk) : (len > 0 ? se.y - 1 : 0);
            r[k] = perm2[pos];
        }
#pragma unroll
        for (int k = 0; k < 8; ++k)
            hv[k] = h32[(size_t)(r[k].x & 0xFFFF) * 32 + f2];
#pragma unroll
        for (int k = 0; k < 8; ++k) {
            float w = (u + k < len) ? __int_as_float(r[k].y) : 0.f;
            a0 += w * bf2f_lo(hv[k]);
            a1 += w * bf2f_hi(hv[k]);
        }
    }
    if (node < n_nodes) {
        float2 o; o.x = a0; o.y = a1;
        *((float2*)&out[(size_t)node * OUT_FEATS + 2 * f2]) = o;
    }
}

// ------- Fallback atomic scatter -------
__global__ __launch_bounds__(256) void scatter_kernel(
    const unsigned short* __restrict__ h, const int* __restrict__ esrc,
    const int* __restrict__ edst, const float* __restrict__ ew,
    float* __restrict__ out, int n_edges)
{
    const int lane = threadIdx.x & 63;
    const int wave = threadIdx.x >> 6;
    const int stride = gridDim.x * 4;
    for (int e = blockIdx.x * 4 + wave; e < n_edges; e += stride) {
        const int s = esrc[e];
        const int d = edst[e];
        const float w = ew[e];
        atomicAdd(out + (size_t)d * OUT_FEATS + lane,
                  bf2f_lo((unsigned)h[(size_t)s * OUT_FEATS + lane]) * w);
    }
}

extern "C" void kernel_launch(void* const* d_in, const int* in_sizes, int n_in,
                              void* d_out, int out_size, void* d_ws, size_t ws_size,
                              hipStream_t stream) {
    const float* feat = (const float*)d_in[0];
    const int*   esrc = (const int*)d_in[1];
    const int*   edst = (const int*)d_in[2];
    const float* ew   = (const float*)d_in[3];
    const float* W    = (const float*)d_in[4];
    const float* b    = (const float*)d_in[5];
    float* out = (float*)d_out;

    const int n_nodes = in_sizes[0] / IN_FEATS;  // 50000
    const int n_edges = in_sizes[1];             // 800000
    const int nb = (n_nodes + BWIDTH - 1) >> BW_LOG;  // 782
    const int nlin = (n_nodes + TM - 1) / TM;         // 782
    const int nstage = (n_edges + SE_PER_BLK - 1) / SE_PER_BLK;  // 98

    // ws: h(bf16 n*64) | ghist(nb) | goff(nb+1) | gcur(nb) | seg(n int2) | gstage
    char* wsb = (char*)d_ws;
    unsigned short* h = (unsigned short*)wsb;
    size_t off_ghist = (((size_t)n_nodes * OUT_FEATS * sizeof(unsigned short)) + 15) & ~(size_t)15;
    size_t sz_ghist  = (((size_t)nb * sizeof(int)) + 15) & ~(size_t)15;
    size_t off_goff  = off_ghist + sz_ghist;
    size_t sz_goff   = (((size_t)(nb + 1) * sizeof(int)) + 15) & ~(size_t)15;
    size_t off_gcur  = off_goff + sz_goff;
    size_t sz_gcur   = (((size_t)nb * sizeof(int)) + 15) & ~(size_t)15;
    size_t off_seg   = off_gcur + sz_gcur;
    size_t sz_seg    = (((size_t)n_nodes * sizeof(int2)) + 15) & ~(size_t)15;
    size_t off_stage = off_seg + sz_seg;
    size_t needed    = off_stage + (size_t)n_edges * sizeof(int2);

    bool binnable = (nb <= MAX_NB) && (n_nodes < 65536) &&
                    ((size_t)n_edges / (size_t)nb * 2 + 256 <= MAX_BUCKET);

    if (ws_size >= needed && binnable) {
        int*  ghist  = (int*)(wsb + off_ghist);
        int*  goff   = (int*)(wsb + off_goff);
        int*  gcur   = (int*)(wsb + off_gcur);
        int2* seg    = (int2*)(wsb + off_seg);
        int2* gstage = (int2*)(wsb + off_stage);
        hipMemsetAsync(ghist, 0, (size_t)nb * sizeof(int), stream);
        coarse_hist<<<128, 256, 0, stream>>>(edst, ghist, n_edges, nb);
        coarse_scan<<<1, 256, 0, stream>>>(ghist, goff, gcur, nb);
        stage_linear<<<nstage + nlin, 256, 0, stream>>>(
            feat, W, b, h, esrc, edst, ew, gcur, gstage,
            n_nodes, n_edges, nb, nstage);
        bin_sort<<<nb, 256, 0, stream>>>(gstage, goff, seg, n_nodes, nb);
        const int gwaves = (n_nodes + 1) / 2;
        gather_kernel<<<(gwaves + 3) / 4, 256, 0, stream>>>(
            h, seg, gstage, out, n_nodes);
    } else {
        // fallback: linear only (nstage=0), then atomic scatter
        stage_linear<<<nlin, 256, 0, stream>>>(
            feat, W, b, h, esrc, edst, ew, nullptr, nullptr,
            n_nodes, n_edges, nb, 0);
        hipMemsetAsync(d_out, 0, (size_t)out_size * sizeof(float), stream);
        scatter_kernel<<<8192, 256, 0, stream>>>(h, esrc, edst, ew, out, n_edges);
    }
}